// Round 1
// baseline (9708.934 us; speedup 1.0000x reference)
//
#include <hip/hip_runtime.h>
#include <hip/hip_fp16.h>
#include <cstdint>
#include <cstddef>

#define NB 32
#define NT 128
#define NH 256
#define NV 32000

typedef _Float16 f16x8 __attribute__((ext_vector_type(8)));
typedef float f32x4 __attribute__((ext_vector_type(4)));

#define SCORES_OFF 0ULL
#define MEM_OFF   131072000ULL
#define ATT_OFF   131080192ULL
#define CTX_OFF   131604480ULL

// ---------------- grid barrier: 8 leaves (16 WGs each) + root, agent scope ----------------
__device__ __forceinline__ void grid_barrier(unsigned* bar) {
  __syncthreads();
  if (threadIdx.x == 0) {
    unsigned* leaf = bar + (blockIdx.x & 7) * 32;   // 128B-separated counters
    unsigned* root = bar + 8 * 32;
    unsigned* gen  = bar + 9 * 32;
    unsigned g = __hip_atomic_load(gen, __ATOMIC_RELAXED, __HIP_MEMORY_SCOPE_AGENT);
    unsigned a = __hip_atomic_fetch_add(leaf, 1u, __ATOMIC_ACQ_REL, __HIP_MEMORY_SCOPE_AGENT);
    if (a == 15u) {
      __hip_atomic_store(leaf, 0u, __ATOMIC_RELAXED, __HIP_MEMORY_SCOPE_AGENT);
      unsigned r = __hip_atomic_fetch_add(root, 1u, __ATOMIC_ACQ_REL, __HIP_MEMORY_SCOPE_AGENT);
      if (r == 7u) {
        __hip_atomic_store(root, 0u, __ATOMIC_RELAXED, __HIP_MEMORY_SCOPE_AGENT);
        __hip_atomic_fetch_add(gen, 1u, __ATOMIC_RELEASE, __HIP_MEMORY_SCOPE_AGENT);
      } else {
        while (__hip_atomic_load(gen, __ATOMIC_ACQUIRE, __HIP_MEMORY_SCOPE_AGENT) == g)
          __builtin_amdgcn_s_sleep(2);
      }
    } else {
      while (__hip_atomic_load(gen, __ATOMIC_ACQUIRE, __HIP_MEMORY_SCOPE_AGENT) == g)
        __builtin_amdgcn_s_sleep(2);
    }
  }
  __syncthreads();
}

// ---------------- embed: enc = relu(table[ids]); write batch-major + [t][h][b] ----------------
__global__ __launch_bounds__(256, 1)
void k_embed(const int* __restrict__ ids, const float* __restrict__ table,
             float* __restrict__ enc_bm, float* __restrict__ enc_tm) {
  __shared__ float lds[256 * 33];
  const int t = blockIdx.x;
  const int h = threadIdx.x;
  for (int b = 0; b < NB; ++b) {
    int id = ids[b * NT + t];
    float v = table[(size_t)id * NH + h];
    v = v > 0.f ? v : 0.f;
    enc_bm[((size_t)b * NT + t) * NH + h] = v;
    lds[h * 33 + b] = v;
  }
  __syncthreads();
  float* dst = enc_tm + (size_t)t * (NH * NB);
  #pragma unroll
  for (int j = 0; j < 32; j += 4) {
    float4 val;
    val.x = lds[h * 33 + j + 0];
    val.y = lds[h * 33 + j + 1];
    val.z = lds[h * 33 + j + 2];
    val.w = lds[h * 33 + j + 3];
    *(float4*)&dst[h * 32 + j] = val;
  }
}

// ---------------- persistent scan: 128 WGs x 256 threads, 4 grid barriers/step ----------------
__global__ __launch_bounds__(256, 1)
void k_scan(const float* __restrict__ memory, const int* __restrict__ xs_len,
            const float* __restrict__ w_ih, const float* __restrict__ w_hh,
            const float* __restrict__ b_ih, const float* __restrict__ b_hh,
            const float* __restrict__ attn_l1, const float* __restrict__ attn_l2,
            const float* __restrict__ lin1_w, const float* __restrict__ lin1_b,
            unsigned* __restrict__ bar,
            const float* __restrict__ enc_bm, const float* __restrict__ enc_tm,
            float* __restrict__ h_buf0, float* __restrict__ h_buf1,
            float* __restrict__ ctx_buf0, float* __restrict__ ctx_buf1,
            float* __restrict__ ctxw, float* __restrict__ xq_bm,
            _Float16* __restrict__ A16, float* __restrict__ d_out) {
  extern __shared__ float sm[];
  const int TSOFF = 128 * 257;              // enc LDS region (WGs 0..31)
  float* xq_lds   = sm + TSOFF;             // 256
  float* attn_lds = sm + TSOFF + 256;       // 128
  float* red      = sm + TSOFF + 384;       // 16
  float* gx       = sm + TSOFF + 448;       // 256
  float* pp       = sm + TSOFF + 704;       // 256

  const int tid  = threadIdx.x;
  const int wg   = blockIdx.x;              // 0..127
  const int wave = tid >> 6;                // 0..3
  const int half_ = (tid >> 5) & 1;
  const int bl   = tid & 31;                // batch lane

  // ---- init ----
  if (wg < 32) {
    const float* src = enc_bm + (size_t)wg * NT * NH;
    for (int idx = tid; idx < NT * NH; idx += 256) {
      int s = idx >> 8, h = idx & 255;
      sm[s * 257 + h] = src[idx];
    }
  } else if (wg < 64) {
    int b = wg - 32;
    for (int i = tid; i < NH; i += 256) h_buf0[i * NB + b] = memory[b * NH + i];
  } else if (wg < 96) {
    int b = wg - 64;
    for (int i = tid; i < NH; i += 256) ctx_buf0[i * NB + b] = 0.f;
  }
  const int len_b = (wg < 32) ? xs_len[wg] : 0;
  grid_barrier(bar);

  for (int t = 0; t < NT; ++t) {
    const int p = t & 1;
    const float* hcur = p ? h_buf1 : h_buf0;
    float*       hnew = p ? h_buf0 : h_buf1;
    const float* ccur = p ? ctx_buf1 : ctx_buf0;
    float*       cnew = p ? ctx_buf0 : ctx_buf1;

    // ---- P1a: s1 for step t-1 (wave 0, rows i = 2*wg + half) ----
    if (t > 0 && wave == 0) {
      const int i = (wg << 1) | half_;
      const float* wr = lin1_w + (size_t)i * NH;
      float a0 = 0.f, a1 = 0.f, a2 = 0.f, a3 = 0.f;
      #pragma unroll 4
      for (int k = 0; k < NH; k += 4) {
        const float4 w4 = *(const float4*)(wr + k);
        a0 += w4.x * ccur[(k + 0) * NB + bl];
        a1 += w4.y * ccur[(k + 1) * NB + bl];
        a2 += w4.z * ccur[(k + 2) * NB + bl];
        a3 += w4.w * ccur[(k + 3) * NB + bl];
      }
      float s1v = tanhf(lin1_b[i] + ((a0 + a1) + (a2 + a3)));
      A16[(size_t)((t - 1) * NB + bl) * NH + i] = (_Float16)s1v;
    }

    // ---- P1b: gates (wave = gate block, rows j = wave*256 + 2*wg + half) ----
    {
      const int jj = (wg << 1) | half_;
      const int j  = (wave << 8) + jj;
      const float* wih = w_ih + (size_t)j * (2 * NH);
      const float* whh = w_hh + (size_t)j * NH;
      const float* xr  = enc_tm + (size_t)t * (NH * NB);
      float a0 = 0.f, a1 = 0.f, a2 = 0.f, a3 = 0.f;
      #pragma unroll 4
      for (int k = 0; k < NH; k += 4) {
        const float4 w4 = *(const float4*)(wih + k);
        a0 += w4.x * xr[(k + 0) * NB + bl];
        a1 += w4.y * xr[(k + 1) * NB + bl];
        a2 += w4.z * xr[(k + 2) * NB + bl];
        a3 += w4.w * xr[(k + 3) * NB + bl];
      }
      #pragma unroll 4
      for (int k = 0; k < NH; k += 4) {
        const float4 w4 = *(const float4*)(wih + NH + k);
        a0 += w4.x * ccur[(k + 0) * NB + bl];
        a1 += w4.y * ccur[(k + 1) * NB + bl];
        a2 += w4.z * ccur[(k + 2) * NB + bl];
        a3 += w4.w * ccur[(k + 3) * NB + bl];
      }
      #pragma unroll 4
      for (int k = 0; k < NH; k += 4) {
        const float4 w4 = *(const float4*)(whh + k);
        a0 += w4.x * hcur[(k + 0) * NB + bl];
        a1 += w4.y * hcur[(k + 1) * NB + bl];
        a2 += w4.z * hcur[(k + 2) * NB + bl];
        a3 += w4.w * hcur[(k + 3) * NB + bl];
      }
      gx[tid] = b_ih[j] + b_hh[j] + ((a0 + a1) + (a2 + a3));
    }
    __syncthreads();
    // h_new (wave 0 lanes: j' = 2*wg + half)
    if (wave == 0) {
      const float gi = gx[tid];
      const float gf = gx[64 + tid];
      const float gg = gx[128 + tid];
      const float go = gx[192 + tid];
      const float si = 1.f / (1.f + expf(-gi));
      const float sf = 1.f / (1.f + expf(-gf));
      const float so = 1.f / (1.f + expf(-go));
      const float gt = tanhf(gg);
      const int jj = (wg << 1) | half_;
      const float hprev = hcur[jj * NB + bl];
      const float cn = sf * hprev + si * gt;
      hnew[jj * NB + bl] = so * tanhf(cn);
    }
    grid_barrier(bar);   // B1: h_new ready

    // ---- P2: xq rows i = 2*wg + half, k split by wave ----
    {
      const int i = (wg << 1) | half_;
      const float* ar = attn_l1 + (size_t)i * NH + wave * 64;
      const int kb = wave * 64;
      float a0 = 0.f, a1 = 0.f, a2 = 0.f, a3 = 0.f;
      #pragma unroll 4
      for (int k = 0; k < 64; k += 4) {
        const float4 w4 = *(const float4*)(ar + k);
        a0 += w4.x * hnew[(kb + k + 0) * NB + bl];
        a1 += w4.y * hnew[(kb + k + 1) * NB + bl];
        a2 += w4.z * hnew[(kb + k + 2) * NB + bl];
        a3 += w4.w * hnew[(kb + k + 3) * NB + bl];
      }
      pp[tid] = (a0 + a1) + (a2 + a3);
    }
    __syncthreads();
    if (wave == 0) {
      const float xqv = pp[tid] + pp[64 + tid] + pp[128 + tid] + pp[192 + tid];
      const int i = (wg << 1) | half_;
      xq_bm[bl * NH + i] = xqv;
    }
    grid_barrier(bar);   // B2: xq ready

    // ---- P3: attention (WGs 0..31, batch b = wg) ----
    if (wg < 32) {
      const int b = wg;
      for (int i = tid; i < NH; i += 256) xq_lds[i] = xq_bm[b * NH + i];
      __syncthreads();
      // att partials: (kh, s) over 256 threads
      {
        const int s = tid & 127, kh = tid >> 7;
        const float* er  = &sm[s * 257 + kh * 128];
        const float* xqp = &xq_lds[kh * 128];
        float a0 = 0.f, a1 = 0.f, a2 = 0.f, a3 = 0.f;
        #pragma unroll 4
        for (int h2 = 0; h2 < 128; h2 += 4) {
          a0 += er[h2 + 0] * xqp[h2 + 0];
          a1 += er[h2 + 1] * xqp[h2 + 1];
          a2 += er[h2 + 2] * xqp[h2 + 2];
          a3 += er[h2 + 3] * xqp[h2 + 3];
        }
        pp[tid] = (a0 + a1) + (a2 + a3);
      }
      __syncthreads();
      float attval = -1e10f;
      if (tid < 128) {
        float a = pp[tid] + pp[128 + tid];
        float m = (tid < len_b) ? a : 0.f;        // seq_mask * att
        if (m == 0.f) m = -1e10f;                 // where(masked==0, -1e10)
        attval = m;
        float v = attval;
        #pragma unroll
        for (int o = 32; o; o >>= 1) v = fmaxf(v, __shfl_xor(v, o, 64));
        if ((tid & 63) == 0) red[tid >> 6] = v;
      }
      __syncthreads();
      const float mx = fmaxf(red[0], red[1]);
      float ex = 0.f;
      if (tid < 128) {
        ex = expf(attval - mx);
        float v = ex;
        #pragma unroll
        for (int o = 32; o; o >>= 1) v += __shfl_xor(v, o, 64);
        if ((tid & 63) == 0) red[2 + (tid >> 6)] = v;
      }
      __syncthreads();
      const float denom = red[2] + red[3];
      if (tid < 128) {
        const float pa = ex / denom;
        attn_lds[tid] = pa;
        d_out[ATT_OFF + ((size_t)t * NT + tid) * NB + b] = pa;   // (T,S,B)
      }
      __syncthreads();
      // ctx_new[i] = sum_s attn[s]*enc[s][i]
      {
        float c = 0.f;
        const int i = tid;
        #pragma unroll 4
        for (int s = 0; s < 128; ++s) c += attn_lds[s] * sm[s * 257 + i];
        ctxw[i * NB + b] = c;
      }
    }
    grid_barrier(bar);   // B3: ctx_new ready

    // ---- P4: ctx2 rows i = 2*wg + half, 512-dot split by wave ----
    {
      const int i = (wg << 1) | half_;
      const float* a2p = attn_l2 + (size_t)i * (2 * NH) + wave * 128;
      const float* src = (wave < 2) ? ctxw : hnew;
      const int kb = (wave < 2) ? wave * 128 : (wave - 2) * 128;
      float a0 = 0.f, a1 = 0.f, a2 = 0.f, a3 = 0.f;
      #pragma unroll 4
      for (int k = 0; k < 128; k += 4) {
        const float4 w4 = *(const float4*)(a2p + k);
        a0 += w4.x * src[(kb + k + 0) * NB + bl];
        a1 += w4.y * src[(kb + k + 1) * NB + bl];
        a2 += w4.z * src[(kb + k + 2) * NB + bl];
        a3 += w4.w * src[(kb + k + 3) * NB + bl];
      }
      pp[tid] = (a0 + a1) + (a2 + a3);
    }
    __syncthreads();
    if (wave == 0) {
      const float c2 = tanhf(pp[tid] + pp[64 + tid] + pp[128 + tid] + pp[192 + tid]);
      const int i = (wg << 1) | half_;
      cnew[i * NB + bl] = c2;
    }
    grid_barrier(bar);   // B4: ctx2 ready
  }

  // ---- epilogue: final s1 (t=127), memory_out, ctxT ----
  const float* cfin = ctx_buf0;   // T even -> final writes landed in buf0
  const float* hfin = h_buf0;
  if (wave == 0) {
    const int i = (wg << 1) | half_;
    const float* wr = lin1_w + (size_t)i * NH;
    float a0 = 0.f, a1 = 0.f, a2 = 0.f, a3 = 0.f;
    #pragma unroll 4
    for (int k = 0; k < NH; k += 4) {
      const float4 w4 = *(const float4*)(wr + k);
      a0 += w4.x * cfin[(k + 0) * NB + bl];
      a1 += w4.y * cfin[(k + 1) * NB + bl];
      a2 += w4.z * cfin[(k + 2) * NB + bl];
      a3 += w4.w * cfin[(k + 3) * NB + bl];
    }
    float s1v = tanhf(lin1_b[i] + ((a0 + a1) + (a2 + a3)));
    A16[(size_t)(127 * NB + bl) * NH + i] = (_Float16)s1v;
  }
  if (wg >= 32 && wg < 64) {
    const int b = wg - 32;
    for (int i = tid; i < NH; i += 256) d_out[MEM_OFF + b * NH + i] = hfin[i * NB + b];
  }
  if (wg >= 64 && wg < 96) {
    const int b = wg - 64;
    for (int i = tid; i < NH; i += 256) d_out[CTX_OFF + b * NH + i] = cfin[i * NB + b];
  }
}

// ---------------- fp16 MFMA GEMM: C[(t,b)][v] = s1 . lin2_w[v] + b2[v] ----------------
__global__ __launch_bounds__(256, 2)
void k_gemm(const _Float16* __restrict__ A, const float* __restrict__ Wf,
            const float* __restrict__ bias, float* __restrict__ out) {
  __shared__ _Float16 As[128 * 64];
  __shared__ _Float16 Ws[128 * 64];
  const int tid = threadIdx.x;
  const int lane = tid & 63;
  const int wave = tid >> 6;
  const int wm = wave >> 1, wn = wave & 1;
  const int m0 = blockIdx.x * 128;   // 32 M-tiles
  const int n0 = blockIdx.y * 128;   // 250 N-tiles

  f32x4 acc[4][4] = {};

  for (int k0 = 0; k0 < 256; k0 += 64) {
    // stage A (fp16, vector copy)
    #pragma unroll
    for (int i = 0; i < 4; ++i) {
      const int flat = (i * 256 + tid) * 8;
      const int r = flat >> 6, c = flat & 63;
      *(float4*)&As[flat] = *(const float4*)(A + (size_t)(m0 + r) * 256 + k0 + c);
    }
    // stage W (fp32 -> fp16 convert in flight)
    #pragma unroll
    for (int i = 0; i < 4; ++i) {
      const int flat = (i * 256 + tid) * 8;
      const int r = flat >> 6, c = flat & 63;
      const float* wrow = Wf + (size_t)(n0 + r) * 256 + k0 + c;
      const float4 f0 = *(const float4*)(wrow);
      const float4 f1 = *(const float4*)(wrow + 4);
      f16x8 hv;
      hv[0] = (_Float16)f0.x; hv[1] = (_Float16)f0.y; hv[2] = (_Float16)f0.z; hv[3] = (_Float16)f0.w;
      hv[4] = (_Float16)f1.x; hv[5] = (_Float16)f1.y; hv[6] = (_Float16)f1.z; hv[7] = (_Float16)f1.w;
      *(f16x8*)&Ws[flat] = hv;
    }
    __syncthreads();
    #pragma unroll
    for (int kk = 0; kk < 2; ++kk) {
      f16x8 af[4], bf[4];
      #pragma unroll
      for (int m = 0; m < 4; ++m)
        af[m] = *(f16x8*)&As[(wm * 64 + m * 16 + (lane & 15)) * 64 + kk * 32 + (lane >> 4) * 8];
      #pragma unroll
      for (int n = 0; n < 4; ++n)
        bf[n] = *(f16x8*)&Ws[(wn * 64 + n * 16 + (lane & 15)) * 64 + kk * 32 + (lane >> 4) * 8];
      #pragma unroll
      for (int m = 0; m < 4; ++m)
        #pragma unroll
        for (int n = 0; n < 4; ++n)
          acc[m][n] = __builtin_amdgcn_mfma_f32_16x16x32_f16(af[m], bf[n], acc[m][n], 0, 0, 0);
    }
    __syncthreads();
  }

  // epilogue: bias + scatter to (B,T,V) layout; rows are rr = t*32+b
  #pragma unroll
  for (int n = 0; n < 4; ++n) {
    const int v = n0 + wn * 64 + n * 16 + (lane & 15);
    const float bv = bias[v];
    #pragma unroll
    for (int m = 0; m < 4; ++m) {
      const int rbase = m0 + wm * 64 + m * 16 + (lane >> 4) * 4;
      #pragma unroll
      for (int r = 0; r < 4; ++r) {
        const int rr = rbase + r;
        const int bb = rr & 31, tt = rr >> 5;
        out[((size_t)bb * NT + tt) * NV + v] = acc[m][n][r] + bv;
      }
    }
  }
}

// ---------------- per-row log_softmax fixup (row in LDS, 1 read + 1 write) ----------------
__global__ __launch_bounds__(512, 1)
void k_lsm(float* __restrict__ out) {
  extern __shared__ float row[];          // 32000 floats
  __shared__ float red2[16];
  const int r = blockIdx.x;               // treated as flat row of (B*T, V)
  float* rp = out + (size_t)r * NV;
  const int tid = threadIdx.x;

  float mx = -INFINITY;
  for (int i = tid * 4; i < NV; i += 2048) {
    const float4 f = *(const float4*)(rp + i);
    *(float4*)&row[i] = f;
    mx = fmaxf(mx, fmaxf(fmaxf(f.x, f.y), fmaxf(f.z, f.w)));
  }
  #pragma unroll
  for (int o = 32; o; o >>= 1) mx = fmaxf(mx, __shfl_xor(mx, o, 64));
  if ((tid & 63) == 0) red2[tid >> 6] = mx;
  __syncthreads();
  mx = red2[0];
  #pragma unroll
  for (int w = 1; w < 8; ++w) mx = fmaxf(mx, red2[w]);

  float s = 0.f;
  for (int i = tid * 4; i < NV; i += 2048) {
    const float4 f = *(const float4*)&row[i];
    s += expf(f.x - mx) + expf(f.y - mx) + expf(f.z - mx) + expf(f.w - mx);
  }
  #pragma unroll
  for (int o = 32; o; o >>= 1) s += __shfl_xor(s, o, 64);
  if ((tid & 63) == 0) red2[8 + (tid >> 6)] = s;
  __syncthreads();
  s = 0.f;
  #pragma unroll
  for (int w = 0; w < 8; ++w) s += red2[8 + w];

  const float corr = mx + logf(s);
  for (int i = tid * 4; i < NV; i += 2048) {
    float4 f = *(const float4*)&row[i];
    f.x -= corr; f.y -= corr; f.z -= corr; f.w -= corr;
    *(float4*)(rp + i) = f;
  }
}

// ---------------- host launcher ----------------
extern "C" void kernel_launch(void* const* d_in, const int* in_sizes, int n_in,
                              void* d_out, int out_size, void* d_ws, size_t ws_size,
                              hipStream_t stream) {
  const float* memory   = (const float*)d_in[0];
  const int*   enc_ids  = (const int*)d_in[1];
  const int*   xs_len   = (const int*)d_in[2];
  const float* emb_tab  = (const float*)d_in[3];
  const float* w_ih     = (const float*)d_in[4];
  const float* w_hh     = (const float*)d_in[5];
  const float* b_ih     = (const float*)d_in[6];
  const float* b_hh     = (const float*)d_in[7];
  const float* attn_l1  = (const float*)d_in[8];
  const float* attn_l2  = (const float*)d_in[9];
  const float* lin1_w   = (const float*)d_in[10];
  const float* lin1_b   = (const float*)d_in[11];
  const float* lin2_w   = (const float*)d_in[12];
  const float* lin2_b   = (const float*)d_in[13];
  float* out = (float*)d_out;

  char* ws = (char*)d_ws;
  unsigned* bar  = (unsigned*)ws;                       // 4096 B barrier region
  float* enc_bm  = (float*)(ws + 4096);                 // B*T*H
  float* enc_tm  = enc_bm + NB * NT * NH;               // T*H*B
  float* h0b     = enc_tm + NT * NH * NB;
  float* h1b     = h0b + NH * NB;
  float* c0b     = h1b + NH * NB;
  float* c1b     = c0b + NH * NB;
  float* ctxw    = c1b + NH * NB;
  float* xq_bm   = ctxw + NH * NB;
  _Float16* A16  = (_Float16*)(xq_bm + NH * NB);        // 4096 x 256 fp16
  // total ws use ~10.7 MB

  (void)in_sizes; (void)n_in; (void)out_size; (void)ws_size;

  hipMemsetAsync(bar, 0, 4096, stream);

  k_embed<<<NT, 256, 0, stream>>>(enc_ids, emb_tab, enc_bm, enc_tm);

  const int scan_lds = (128 * 257 + 1024) * 4;          // 135,680 B
  hipFuncSetAttribute((const void*)k_scan, hipFuncAttributeMaxDynamicSharedMemorySize, scan_lds);
  k_scan<<<128, 256, scan_lds, stream>>>(memory, xs_len, w_ih, w_hh, b_ih, b_hh,
                                         attn_l1, attn_l2, lin1_w, lin1_b, bar,
                                         enc_bm, enc_tm, h0b, h1b, c0b, c1b,
                                         ctxw, xq_bm, A16, out);

  k_gemm<<<dim3(32, 250), 256, 0, stream>>>(A16, lin2_w, lin2_b, out);

  const int lsm_lds = NV * 4;                           // 128,000 B
  hipFuncSetAttribute((const void*)k_lsm, hipFuncAttributeMaxDynamicSharedMemorySize, lsm_lds);
  k_lsm<<<NB * NT, 512, lsm_lds, stream>>>(out);
}

// Round 2
// 6382.695 us; speedup vs baseline: 1.5211x; 1.5211x over previous
//
#include <hip/hip_runtime.h>
#include <hip/hip_fp16.h>
#include <stdint.h>
#include <stddef.h>

#define NB 32
#define NT 128
#define NH 256
#define NV 32000

typedef _Float16 f16x8 __attribute__((ext_vector_type(8)));
typedef float f32x4 __attribute__((ext_vector_type(4)));

#define MEM_OFF   131072000ULL
#define ATT_OFF   131080192ULL
#define CTX_OFF   131604480ULL

// ---- tagged relaxed agent atomics: no fences, no L2 flush ----
__device__ __forceinline__ void tstore(unsigned long long* p, unsigned tag, float v) {
  unsigned long long u = ((unsigned long long)tag << 32) | (unsigned long long)__float_as_uint(v);
  __hip_atomic_store(p, u, __ATOMIC_RELAXED, __HIP_MEMORY_SCOPE_AGENT);
}
__device__ __forceinline__ unsigned long long tload(const unsigned long long* p) {
  return __hip_atomic_load(p, __ATOMIC_RELAXED, __HIP_MEMORY_SCOPE_AGENT);
}

// stage 8192-entry tagged buffer [k*32+b] -> LDS dst[b*260+k]; thread tid owns k=tid, b=0..31
__device__ __forceinline__ void stage32(const unsigned long long* src, float* dstL, int tid, unsigned tag) {
  const unsigned long long* s = src + (size_t)tid * 32;
  unsigned bad = 0;
  #pragma unroll
  for (int i = 0; i < 32; ++i) {
    unsigned long long u = tload(s + i);
    dstL[i * 260 + tid] = __uint_as_float((unsigned)u);
    bad |= ((unsigned)(u >> 32) != tag) ? (1u << i) : 0u;
  }
  while (bad) {
    __builtin_amdgcn_s_sleep(1);
    #pragma unroll
    for (int i = 0; i < 32; ++i) {
      if (bad & (1u << i)) {
        unsigned long long u = tload(s + i);
        if ((unsigned)(u >> 32) == tag) { dstL[i * 260 + tid] = __uint_as_float((unsigned)u); bad &= ~(1u << i); }
      }
    }
  }
}

// ---------------- embed: enc = relu(table[ids]); [b][t][h] and [t][b][h] ----------------
__global__ __launch_bounds__(256, 1)
void k_embed(const int* __restrict__ ids, const float* __restrict__ table,
             float* __restrict__ enc_bm, float* __restrict__ enc_tbk) {
  const int t = blockIdx.x;
  const int h = threadIdx.x;
  for (int b = 0; b < NB; ++b) {
    int id = ids[b * NT + t];
    float v = table[(size_t)id * NH + h];
    v = v > 0.f ? v : 0.f;
    enc_bm[((size_t)b * NT + t) * NH + h] = v;
    enc_tbk[((size_t)t * NB + b) * NH + h] = v;
  }
}

// ---------------- persistent dataflow scan: 32 attn WGs + 128 GEMV WGs, ZERO fences ----------------
__global__ __launch_bounds__(256, 1)
void k_scan(const float* __restrict__ memory, const int* __restrict__ xs_len,
            const float* __restrict__ w_ih, const float* __restrict__ w_hh,
            const float* __restrict__ b_ih, const float* __restrict__ b_hh,
            const float* __restrict__ attn_l1, const float* __restrict__ attn_l2,
            const float* __restrict__ lin1_w, const float* __restrict__ lin1_b,
            const float* __restrict__ enc_bm, const float* __restrict__ enc_tbk,
            unsigned long long* __restrict__ h2,   // [2][256][32]
            unsigned long long* __restrict__ c2,   // [2][256][32]
            unsigned long long* __restrict__ xqb,  // [256][32]
            unsigned long long* __restrict__ cw,   // [256][32]
            _Float16* __restrict__ A16, float* __restrict__ d_out) {
  extern __shared__ float sm[];
  const int tid = threadIdx.x;
  const int wg = blockIdx.x;

  if (wg < 32) {
    // ================= attention WG: batch b = wg =================
    const int b = wg;
    float* xqL      = sm + 32896;   // 256
    float* attn_lds = sm + 33152;   // 128
    float* red      = sm + 33280;   // 16
    float* pp       = sm + 33296;   // 256
    {
      const float* src = enc_bm + (size_t)b * NT * NH;
      for (int idx = tid; idx < NT * NH; idx += 256)
        sm[(idx >> 8) * 257 + (idx & 255)] = src[idx];
    }
    const int len_b = xs_len[b];

    for (int t = 0; t < NT; ++t) {
      const unsigned tag = (unsigned)(t + 2);
      // stage xq[.][b] (1 tagged value per thread)
      {
        const unsigned long long* p = xqb + (size_t)tid * 32 + b;
        unsigned long long u;
        for (;;) { u = tload(p); if ((unsigned)(u >> 32) == tag) break; }
        xqL[tid] = __uint_as_float((unsigned)u);
      }
      __syncthreads();
      // att partials over (kh, s)
      {
        const int s = tid & 127, kh = tid >> 7;
        const float* er = &sm[s * 257 + kh * 128];
        const float* xp = &xqL[kh * 128];
        float a0 = 0.f, a1 = 0.f, a2 = 0.f, a3 = 0.f;
        #pragma unroll 4
        for (int h2i = 0; h2i < 128; h2i += 4) {
          a0 += er[h2i + 0] * xp[h2i + 0];
          a1 += er[h2i + 1] * xp[h2i + 1];
          a2 += er[h2i + 2] * xp[h2i + 2];
          a3 += er[h2i + 3] * xp[h2i + 3];
        }
        pp[tid] = (a0 + a1) + (a2 + a3);
      }
      __syncthreads();
      float attval = -1e10f, ex = 0.f;
      if (tid < 128) {
        float a = pp[tid] + pp[128 + tid];
        float m = (tid < len_b) ? a : 0.f;
        if (m == 0.f) m = -1e10f;
        attval = m;
        float v = m;
        #pragma unroll
        for (int o = 32; o; o >>= 1) v = fmaxf(v, __shfl_xor(v, o, 64));
        if ((tid & 63) == 0) red[tid >> 6] = v;
      }
      __syncthreads();
      if (tid < 128) {
        const float mx = fmaxf(red[0], red[1]);
        ex = expf(attval - mx);
        float v = ex;
        #pragma unroll
        for (int o = 32; o; o >>= 1) v += __shfl_xor(v, o, 64);
        if ((tid & 63) == 0) red[2 + (tid >> 6)] = v;
      }
      __syncthreads();
      if (tid < 128) {
        const float pa = ex / (red[2] + red[3]);
        attn_lds[tid] = pa;
        d_out[ATT_OFF + ((size_t)t * NT + tid) * NB + b] = pa;  // (T,S,B)
      }
      __syncthreads();
      // ctx_new[i] = sum_s attn[s] * enc[s][i]  -> tagged write
      {
        float c = 0.f;
        #pragma unroll 4
        for (int s2 = 0; s2 < 128; ++s2) c += attn_lds[s2] * sm[s2 * 257 + tid];
        tstore(cw + (size_t)tid * 32 + b, tag, c);
      }
      __syncthreads();
    }
    return;
  }

  // ================= GEMV WG: wgg = wg-32 in [0,128) =================
  const int wgg = wg - 32;
  const int bl = tid & 31;
  const int jv = (tid >> 5) & 1;
  const int ks = tid >> 6;          // wave id -> uniform loop bounds per wave
  const int jj = 2 * wgg + jv;

  float* hL   = sm;            // [32][260] h(t-1) -> h(t)
  float* ctxL = sm + 8320;     // [32][260] ctx(t-1) -> ctx(t)
  float* cwL  = sm + 16640;    // [32][260] ctxw(t)
  float* wihL = sm + 24960;    // [8][512]
  float* whhL = sm + 29056;    // [8][256]
  float* a1L  = sm + 31104;    // [2][256]
  float* a2L  = sm + 31616;    // [2][512]
  float* l1L  = sm + 32640;    // [2][256]
  float* ppg  = sm + 33152;    // [256][4]
  float* pp2  = sm + 34176;    // [64][4]
  float* bLs  = sm + 34432;    // 8 gate biases + 2 lin1 biases

  // ---- one-time: weights -> LDS ----
  for (int idx = tid; idx < 8 * 512; idx += 256) {
    int r = idx >> 9, k = idx & 511;
    wihL[idx] = w_ih[(size_t)((r >> 1) * 256 + 2 * wgg + (r & 1)) * 512 + k];
  }
  for (int idx = tid; idx < 8 * 256; idx += 256) {
    int r = idx >> 8, k = idx & 255;
    whhL[idx] = w_hh[(size_t)((r >> 1) * 256 + 2 * wgg + (r & 1)) * 256 + k];
  }
  for (int idx = tid; idx < 2 * 256; idx += 256) {
    int r = idx >> 8, k = idx & 255;
    a1L[idx] = attn_l1[(size_t)(2 * wgg + r) * 256 + k];
    l1L[idx] = lin1_w[(size_t)(2 * wgg + r) * 256 + k];
  }
  for (int idx = tid; idx < 2 * 512; idx += 256) {
    int r = idx >> 9, k = idx & 511;
    a2L[idx] = attn_l2[(size_t)(2 * wgg + r) * 512 + k];
  }
  if (tid < 8) {
    int j = (tid >> 1) * 256 + 2 * wgg + (tid & 1);
    bLs[tid] = b_ih[j] + b_hh[j];
  }
  if (tid < 2) bLs[8 + tid] = lin1_b[2 * wgg + tid];

  // ---- init tags: h(-1)=h0 (slot0 tag1), ctx(-1)=0 ----
  if (wgg < 32) {
    tstore(h2 + (size_t)tid * 32 + wgg, 1u, memory[(size_t)wgg * NH + tid]);
  } else if (wgg < 64) {
    tstore(c2 + (size_t)tid * 32 + (wgg - 32), 1u, 0.f);
  }
  stage32(h2, hL, tid, 1u);
  stage32(c2, ctxL, tid, 1u);
  __syncthreads();

  for (int t = 0; t < NT; ++t) {
    const unsigned tag = (unsigned)(t + 2);
    const int slot = (t + 1) & 1;

    // ---- gates: rows {g*256+jj, g=0..3}, k-span [ks*192,(ks+1)*192) over x|ctx|h ----
    {
      const int K0 = ks * 192, K1 = K0 + 192;
      float acc0 = 0.f, acc1 = 0.f, acc2 = 0.f, acc3 = 0.f;
      const float* xg = enc_tbk + ((size_t)t * NB + bl) * NH;
      // X section: k in [K0, min(K1,256))
      {
        int ka = K0, kb = K1 < 256 ? K1 : 256;
        for (int k = ka; k < kb; k += 4) {
          const float4 x4 = *(const float4*)(xg + k);
          const float4 w0 = *(const float4*)&wihL[(jv) * 512 + k];
          const float4 w1 = *(const float4*)&wihL[(2 + jv) * 512 + k];
          const float4 w2 = *(const float4*)&wihL[(4 + jv) * 512 + k];
          const float4 w3 = *(const float4*)&wihL[(6 + jv) * 512 + k];
          acc0 += w0.x * x4.x + w0.y * x4.y + w0.z * x4.z + w0.w * x4.w;
          acc1 += w1.x * x4.x + w1.y * x4.y + w1.z * x4.z + w1.w * x4.w;
          acc2 += w2.x * x4.x + w2.y * x4.y + w2.z * x4.z + w2.w * x4.w;
          acc3 += w3.x * x4.x + w3.y * x4.y + w3.z * x4.z + w3.w * x4.w;
        }
      }
      // CTX section: k in [max(K0,256), min(K1,512))
      {
        int ka = K0 > 256 ? K0 : 256, kb = K1 < 512 ? K1 : 512;
        for (int k = ka; k < kb; k += 4) {
          const float4 x4 = *(const float4*)&ctxL[bl * 260 + (k - 256)];
          const float4 w0 = *(const float4*)&wihL[(jv) * 512 + k];
          const float4 w1 = *(const float4*)&wihL[(2 + jv) * 512 + k];
          const float4 w2 = *(const float4*)&wihL[(4 + jv) * 512 + k];
          const float4 w3 = *(const float4*)&wihL[(6 + jv) * 512 + k];
          acc0 += w0.x * x4.x + w0.y * x4.y + w0.z * x4.z + w0.w * x4.w;
          acc1 += w1.x * x4.x + w1.y * x4.y + w1.z * x4.z + w1.w * x4.w;
          acc2 += w2.x * x4.x + w2.y * x4.y + w2.z * x4.z + w2.w * x4.w;
          acc3 += w3.x * x4.x + w3.y * x4.y + w3.z * x4.z + w3.w * x4.w;
        }
      }
      // H section: k in [max(K0,512), K1)
      {
        int ka = K0 > 512 ? K0 : 512, kb = K1;
        for (int k = ka; k < kb; k += 4) {
          const float4 x4 = *(const float4*)&hL[bl * 260 + (k - 512)];
          const float4 w0 = *(const float4*)&whhL[(jv) * 256 + (k - 512)];
          const float4 w1 = *(const float4*)&whhL[(2 + jv) * 256 + (k - 512)];
          const float4 w2 = *(const float4*)&whhL[(4 + jv) * 256 + (k - 512)];
          const float4 w3 = *(const float4*)&whhL[(6 + jv) * 256 + (k - 512)];
          acc0 += w0.x * x4.x + w0.y * x4.y + w0.z * x4.z + w0.w * x4.w;
          acc1 += w1.x * x4.x + w1.y * x4.y + w1.z * x4.z + w1.w * x4.w;
          acc2 += w2.x * x4.x + w2.y * x4.y + w2.z * x4.z + w2.w * x4.w;
          acc3 += w3.x * x4.x + w3.y * x4.y + w3.z * x4.z + w3.w * x4.w;
        }
      }
      ppg[((jv) * 32 + bl) * 4 + ks] = acc0;
      ppg[((2 + jv) * 32 + bl) * 4 + ks] = acc1;
      ppg[((4 + jv) * 32 + bl) * 4 + ks] = acc2;
      ppg[((6 + jv) * 32 + bl) * 4 + ks] = acc3;
    }
    __syncthreads();
    if (tid < 64) {
      const int jv2 = tid >> 5, bl2 = tid & 31, jj2 = 2 * wgg + jv2;
      float g0 = ppg[(0 * 64 + tid) * 4 + 0] + ppg[(0 * 64 + tid) * 4 + 1] + ppg[(0 * 64 + tid) * 4 + 2] + ppg[(0 * 64 + tid) * 4 + 3] + bLs[jv2];
      float g1 = ppg[(1 * 64 + tid) * 4 + 0] + ppg[(1 * 64 + tid) * 4 + 1] + ppg[(1 * 64 + tid) * 4 + 2] + ppg[(1 * 64 + tid) * 4 + 3] + bLs[2 + jv2];
      float g2 = ppg[(2 * 64 + tid) * 4 + 0] + ppg[(2 * 64 + tid) * 4 + 1] + ppg[(2 * 64 + tid) * 4 + 2] + ppg[(2 * 64 + tid) * 4 + 3] + bLs[4 + jv2];
      float g3 = ppg[(3 * 64 + tid) * 4 + 0] + ppg[(3 * 64 + tid) * 4 + 1] + ppg[(3 * 64 + tid) * 4 + 2] + ppg[(3 * 64 + tid) * 4 + 3] + bLs[6 + jv2];
      const float si = 1.f / (1.f + expf(-g0));
      const float sf = 1.f / (1.f + expf(-g1));
      const float so = 1.f / (1.f + expf(-g3));
      const float gt = tanhf(g2);
      const float hp = hL[bl2 * 260 + jj2];
      const float hv = so * tanhf(sf * hp + si * gt);
      tstore(h2 + (size_t)slot * 8192 + jj2 * 32 + bl2, tag, hv);
    }
    __syncthreads();                       // all reads of old hL done
    stage32(h2 + (size_t)slot * 8192, hL, tid, tag);   // hL <- h(t)
    __syncthreads();

    // ---- xq: row i=jj, k-span 64 ----
    {
      const int kb = ks * 64;
      float a0 = 0.f;
      #pragma unroll 4
      for (int k = 0; k < 64; k += 4) {
        const float4 h4 = *(const float4*)&hL[bl * 260 + kb + k];
        const float4 w4 = *(const float4*)&a1L[jv * 256 + kb + k];
        a0 += w4.x * h4.x + w4.y * h4.y + w4.z * h4.z + w4.w * h4.w;
      }
      pp2[(jv * 32 + bl) * 4 + ks] = a0;
    }
    __syncthreads();
    if (tid < 64) {
      float x = pp2[tid * 4 + 0] + pp2[tid * 4 + 1] + pp2[tid * 4 + 2] + pp2[tid * 4 + 3];
      tstore(xqb + (size_t)(2 * wgg + (tid >> 5)) * 32 + (tid & 31), tag, x);
    }
    __syncthreads();                       // pp2 reads done before ctx2 writes it
    stage32(cw, cwL, tid, tag);            // cwL <- ctxw(t)  (spins on attention)
    __syncthreads();

    // ---- ctx2: row i=jj, k-span 128 over [ctxw | h(t)] ----
    {
      const int kb = ks * 128;
      const float* actp = (ks < 2) ? &cwL[bl * 260 + kb] : &hL[bl * 260 + (kb - 256)];
      float a0 = 0.f;
      #pragma unroll 4
      for (int k = 0; k < 128; k += 4) {
        const float4 x4 = *(const float4*)(actp + k);
        const float4 w4 = *(const float4*)&a2L[jv * 512 + kb + k];
        a0 += w4.x * x4.x + w4.y * x4.y + w4.z * x4.z + w4.w * x4.w;
      }
      pp2[(jv * 32 + bl) * 4 + ks] = a0;
    }
    __syncthreads();
    if (tid < 64) {
      float c = tanhf(pp2[tid * 4 + 0] + pp2[tid * 4 + 1] + pp2[tid * 4 + 2] + pp2[tid * 4 + 3]);
      tstore(c2 + (size_t)slot * 8192 + (2 * wgg + (tid >> 5)) * 32 + (tid & 31), tag, c);
    }
    __syncthreads();                       // all reads of old ctxL done
    stage32(c2 + (size_t)slot * 8192, ctxL, tid, tag); // ctxL <- ctx(t)
    __syncthreads();

    // ---- s1(t) = tanh(lin1 . ctx(t) + b): row i=jj, k-span 64 ----
    {
      const int kb = ks * 64;
      float a0 = 0.f;
      #pragma unroll 4
      for (int k = 0; k < 64; k += 4) {
        const float4 x4 = *(const float4*)&ctxL[bl * 260 + kb + k];
        const float4 w4 = *(const float4*)&l1L[jv * 256 + kb + k];
        a0 += w4.x * x4.x + w4.y * x4.y + w4.z * x4.z + w4.w * x4.w;
      }
      pp2[(jv * 32 + bl) * 4 + ks] = a0;
    }
    __syncthreads();
    if (tid < 64) {
      float s1v = tanhf(pp2[tid * 4 + 0] + pp2[tid * 4 + 1] + pp2[tid * 4 + 2] + pp2[tid * 4 + 3] + bLs[8 + (tid >> 5)]);
      A16[((size_t)t * NB + (tid & 31)) * NH + 2 * wgg + (tid >> 5)] = (_Float16)s1v;
    }
    __syncthreads();
  }

  // ---- epilogue: memory_out (h(127)) and ctxT (ctx(127)) from staged LDS ----
  if (wgg < 32) {
    d_out[MEM_OFF + (size_t)wgg * NH + tid] = hL[wgg * 260 + tid];
  } else if (wgg < 64) {
    d_out[CTX_OFF + (size_t)(wgg - 32) * NH + tid] = ctxL[(wgg - 32) * 260 + tid];
  }
}

// ---------------- fp16 MFMA GEMM: C[(t,b)][v] = s1 . lin2_w[v] + b2[v] ----------------
__global__ __launch_bounds__(256, 2)
void k_gemm(const _Float16* __restrict__ A, const float* __restrict__ Wf,
            const float* __restrict__ bias, float* __restrict__ out) {
  __shared__ _Float16 As[128 * 64];
  __shared__ _Float16 Ws[128 * 64];
  const int tid = threadIdx.x;
  const int lane = tid & 63;
  const int wave = tid >> 6;
  const int wm = wave >> 1, wn = wave & 1;
  const int m0 = blockIdx.x * 128;
  const int n0 = blockIdx.y * 128;

  f32x4 acc[4][4] = {};

  for (int k0 = 0; k0 < 256; k0 += 64) {
    #pragma unroll
    for (int i = 0; i < 4; ++i) {
      const int flat = (i * 256 + tid) * 8;
      const int r = flat >> 6, c = flat & 63;
      *(float4*)&As[flat] = *(const float4*)(A + (size_t)(m0 + r) * 256 + k0 + c);
    }
    #pragma unroll
    for (int i = 0; i < 4; ++i) {
      const int flat = (i * 256 + tid) * 8;
      const int r = flat >> 6, c = flat & 63;
      const float* wrow = Wf + (size_t)(n0 + r) * 256 + k0 + c;
      const float4 f0 = *(const float4*)(wrow);
      const float4 f1 = *(const float4*)(wrow + 4);
      f16x8 hv;
      hv[0] = (_Float16)f0.x; hv[1] = (_Float16)f0.y; hv[2] = (_Float16)f0.z; hv[3] = (_Float16)f0.w;
      hv[4] = (_Float16)f1.x; hv[5] = (_Float16)f1.y; hv[6] = (_Float16)f1.z; hv[7] = (_Float16)f1.w;
      *(f16x8*)&Ws[flat] = hv;
    }
    __syncthreads();
    #pragma unroll
    for (int kk = 0; kk < 2; ++kk) {
      f16x8 af[4], bf[4];
      #pragma unroll
      for (int m = 0; m < 4; ++m)
        af[m] = *(f16x8*)&As[(wm * 64 + m * 16 + (lane & 15)) * 64 + kk * 32 + (lane >> 4) * 8];
      #pragma unroll
      for (int n = 0; n < 4; ++n)
        bf[n] = *(f16x8*)&Ws[(wn * 64 + n * 16 + (lane & 15)) * 64 + kk * 32 + (lane >> 4) * 8];
      #pragma unroll
      for (int m = 0; m < 4; ++m)
        #pragma unroll
        for (int n = 0; n < 4; ++n)
          acc[m][n] = __builtin_amdgcn_mfma_f32_16x16x32_f16(af[m], bf[n], acc[m][n], 0, 0, 0);
    }
    __syncthreads();
  }

  #pragma unroll
  for (int n = 0; n < 4; ++n) {
    const int v = n0 + wn * 64 + n * 16 + (lane & 15);
    const float bv = bias[v];
    #pragma unroll
    for (int m = 0; m < 4; ++m) {
      const int rbase = m0 + wm * 64 + m * 16 + (lane >> 4) * 4;
      #pragma unroll
      for (int r = 0; r < 4; ++r) {
        const int rr = rbase + r;
        const int bb = rr & 31, tt = rr >> 5;
        out[((size_t)bb * NT + tt) * NV + v] = acc[m][n][r] + bv;
      }
    }
  }
}

// ---------------- per-row log_softmax fixup ----------------
__global__ __launch_bounds__(1024, 1)
void k_lsm(float* __restrict__ out) {
  extern __shared__ float row[];          // 32000 floats
  __shared__ float red2[32];
  const int r = blockIdx.x;
  float* rp = out + (size_t)r * NV;
  const int tid = threadIdx.x;

  float mx = -INFINITY;
  for (int i = tid * 4; i < NV; i += 4096) {
    const float4 f = *(const float4*)(rp + i);
    *(float4*)&row[i] = f;
    mx = fmaxf(mx, fmaxf(fmaxf(f.x, f.y), fmaxf(f.z, f.w)));
  }
  #pragma unroll
  for (int o = 32; o; o >>= 1) mx = fmaxf(mx, __shfl_xor(mx, o, 64));
  if ((tid & 63) == 0) red2[tid >> 6] = mx;
  __syncthreads();
  mx = red2[0];
  #pragma unroll
  for (int w = 1; w < 16; ++w) mx = fmaxf(mx, red2[w]);

  float s = 0.f;
  for (int i = tid * 4; i < NV; i += 4096) {
    const float4 f = *(const float4*)&row[i];
    s += expf(f.x - mx) + expf(f.y - mx) + expf(f.z - mx) + expf(f.w - mx);
  }
  #pragma unroll
  for (int o = 32; o; o >>= 1) s += __shfl_xor(s, o, 64);
  if ((tid & 63) == 0) red2[16 + (tid >> 6)] = s;
  __syncthreads();
  s = 0.f;
  #pragma unroll
  for (int w = 0; w < 16; ++w) s += red2[16 + w];

  const float corr = mx + logf(s);
  for (int i = tid * 4; i < NV; i += 4096) {
    float4 f = *(const float4*)&row[i];
    f.x -= corr; f.y -= corr; f.z -= corr; f.w -= corr;
    *(float4*)(rp + i) = f;
  }
}

// ---------------- host launcher ----------------
extern "C" void kernel_launch(void* const* d_in, const int* in_sizes, int n_in,
                              void* d_out, int out_size, void* d_ws, size_t ws_size,
                              hipStream_t stream) {
  const float* memory   = (const float*)d_in[0];
  const int*   enc_ids  = (const int*)d_in[1];
  const int*   xs_len   = (const int*)d_in[2];
  const float* emb_tab  = (const float*)d_in[3];
  const float* w_ih     = (const float*)d_in[4];
  const float* w_hh     = (const float*)d_in[5];
  const float* b_ih     = (const float*)d_in[6];
  const float* b_hh     = (const float*)d_in[7];
  const float* attn_l1  = (const float*)d_in[8];
  const float* attn_l2  = (const float*)d_in[9];
  const float* lin1_w   = (const float*)d_in[10];
  const float* lin1_b   = (const float*)d_in[11];
  const float* lin2_w   = (const float*)d_in[12];
  const float* lin2_b   = (const float*)d_in[13];
  float* out = (float*)d_out;

  unsigned long long* h2  = (unsigned long long*)d_ws;   // 2*8192
  unsigned long long* c2  = h2 + 16384;                  // 2*8192
  unsigned long long* xqb = c2 + 16384;                  // 8192
  unsigned long long* cw  = xqb + 8192;                  // 8192
  _Float16* A16  = (_Float16*)(cw + 8192);               // 4096*256 fp16 = 2MB
  float* enc_bm  = (float*)((char*)A16 + 2097152);       // 4MB
  float* enc_tbk = enc_bm + (size_t)NB * NT * NH;        // 4MB

  (void)in_sizes; (void)n_in; (void)out_size; (void)ws_size;

  k_embed<<<NT, 256, 0, stream>>>(enc_ids, emb_tab, enc_bm, enc_tbk);

  const int scan_lds = 34448 * 4;   // 137,792 B
  hipFuncSetAttribute((const void*)k_scan, hipFuncAttributeMaxDynamicSharedMemorySize, scan_lds);
  k_scan<<<160, 256, scan_lds, stream>>>(memory, xs_len, w_ih, w_hh, b_ih, b_hh,
                                         attn_l1, attn_l2, lin1_w, lin1_b,
                                         enc_bm, enc_tbk, h2, c2, xqb, cw, A16, out);

  k_gemm<<<dim3(32, 250), 256, 0, stream>>>(A16, lin2_w, lin2_b, out);

  const int lsm_lds = NV * 4;       // 128,000 B
  hipFuncSetAttribute((const void*)k_lsm, hipFuncAttributeMaxDynamicSharedMemorySize, lsm_lds);
  k_lsm<<<NB * NT, 1024, lsm_lds, stream>>>(out);
}